// Round 10
// baseline (152.392 us; speedup 1.0000x reference)
//
#include <hip/hip_runtime.h>
#include <math.h>

// Problem: SphericalHarmonicTransform, L=8, RCUT=5, N=4194304 points.
// R19: R18 + #pragma unroll 2 on the point loop (the untested unroll cell).
//     Ladder: unroll 8 = 75us (I$ thrash, 25-40KB body); unroll 1 = 70.5us
//     (I$-resident, zero cross-point ILP). Unroll 2 = ~6-10KB body (I$ safe)
//     with a fully independent second point body for the scheduler to
//     interleave into dep shadows.
//     Evidence this fills real idle slots: R12's single wave hit 30% issue
//     via packed ILP (vs 25%/wave unpacked), and R15's +47 independent muls
//     were FREE (+0.25%) -> dep shadows exist and absorb independent work.
//     Adding WAVES is dead (total busy pinned ~49% at 2 and 2.5 waves/SIMD);
//     adding INTRA-wave ILP is the remaining axis, now without R12's
//     packing/marshalling/VGPR costs.
//     Predicted: VGPR 72 -> 95-130 (guard: WRITE_SIZE ~2.6MB, no spill);
//     if dep-bound: busy 49 -> 62-75%, sht_main 70 -> 52-60us, bench ~115.
//     If flat +-3%: hard ~50% shared issue cap confirmed by exclusion
//     (waves x, ILP x) -> declare structural limit or go algorithmic.
//     Bit-exact: unroll preserves k, k+1 fold order. absmax 0.0.
// Harness facts: 41us unconditional 268MB d_ws poison-fill in timed window
//     (R18: bypass neutral -> unconditional); dur = 41 + main + 4 + ~17.
// Known-good: un-unrolled-ish small bodies (R13); g_ws device scratch (R18,
//     neutral, kept); (256,1).
// Known-bad: occupancy knobs (R9/R11/R15/R16 busy pinned); (256,4) fat-
//     kernel spill (R2); waves_per_eu (R10); f32x4 packing (R12); pair-
//     packed split (R17); (l,m) split (R16, +10us dup work); reshape (R8);
//     fused finalize (R5); prefetch (R4).

typedef float f32x2 __attribute__((ext_vector_type(2)));

#define NL 8               // L
#define NBLK 1024
#define NTHR 256

// module-scope scratch: replaces d_ws (neutral vs d_ws, kept for simplicity).
__device__ float g_ws[81 * NBLK];

__device__ __forceinline__ f32x2 sp(float v) { return f32x2{v, v}; }

__device__ __forceinline__ f32x2 pkfma(f32x2 a, f32x2 b, f32x2 c) {
    return __builtin_elementwise_fma(a, b, c);
}

// a*b with an opaque SSA def: blocks GVN/CSE from rebuilding a table of
// these products across the unrolled m-loop. Zero extra instructions,
// bitwise-identical value.
__device__ __forceinline__ float omul(float a, float b) {
    float r = a * b;
    asm("" : "+v"(r));
    return r;
}

__device__ __forceinline__ float waveReduce(float v) {
    v += __shfl_down(v, 32);
    v += __shfl_down(v, 16);
    v += __shfl_down(v, 8);
    v += __shfl_down(v, 4);
    v += __shfl_down(v, 2);
    v += __shfl_down(v, 1);
    return v;
}

// One point, fully unrolled. acc0 = m=0 reals (9); accp = m>=1 (re,im) pairs (36).
// Arithmetic bit-identical to R9/R13/R15/R18.
__device__ __forceinline__ void point_body(float x, float y, float z,
                                           float* __restrict__ acc0,
                                           f32x2* __restrict__ accp) {
    const float FACT[9] = {1.f, 1.f, 2.f, 6.f, 24.f, 120.f, 720.f, 5040.f, 40320.f};

    const float r2 = x * x + y * y + z * z;
    const bool valid = r2 > 0.0f;
    const float inv0 = __builtin_amdgcn_rsqf(r2);      // 1/sqrt(r2)
    const float norm = r2 * inv0;                      // sqrt(r2); NaN at 0, masked
    float cut = 0.5f * (__cosf(norm * 0.6283185307179586f) + 1.0f);
    cut = (r2 > 25.0f) ? 0.0f : cut;
    cut = valid ? cut : 0.0f;                          // kills NaN at r2=0
    const float inv = valid ? inv0 : 1.0f;             // safe 1/norm
    const float x0c = z * cut;

    // packed chains: lane0 = z1 (xp), lane1 = z2 (xm)
    const f32x2 w  = { -0.5f * x,  0.5f * x };         // (xpr, xmr)
    const f32x2 wi = { -0.5f * y, -0.5f * y };         // (xpi, xmi)

    // powcmplx replication:
    //  n=0 -> (1,0); n=1 -> w; n=2 -> special (r^2-i^2, 2ri);
    //  n>=3 -> buggy chain: nr = wr*br - wi*bi; ni = wr*bi + wi*nr (uses NEW nr)
    f32x2 zr[9], zi[9];
    zr[0] = sp(1.f); zi[0] = sp(0.f);
    zr[1] = w;       zi[1] = wi;
    zr[2] = w * w - wi * wi;
    zi[2] = (w + w) * wi;                              // 2*wr*wi
    {
        f32x2 cr = zr[2];
        f32x2 ci = w * wi + wi * cr;                   // buggy chain imag at k=2
#pragma unroll
        for (int k = 3; k <= NL; ++k) {
            const f32x2 nr = w * cr - wi * ci;
            const f32x2 ni = w * ci + wi * nr;         // buggy: uses nr
            cr = nr; ci = ni;
            zr[k] = nr; zi[k] = ni;
        }
    }

    // unpack views (register aliases, free). No sqa table (R15): aa*aa
    // recomputed at each use via omul (bitwise-identical product).
    float aa[9], bb[9], cc[9], dd[9];
#pragma unroll
    for (int p = 0; p <= NL; ++p) {
        aa[p] = zr[p].x;   // z1r
        cc[p] = zr[p].y;   // z2r
        bb[p] = zi[p].x;   // z1i
        dd[p] = zi[p].y;   // z2i
    }

    // No h table (R15): running products reproduce h[l] = h[l-1]*inv exactly.

    // ---- m = 0: pure-real scalar path (no dead imag work) ----
    {
        float Y0[5];                                    // p = q, p <= 4
#pragma unroll
        for (int p = 0; p <= 4; ++p) {
            const float cpq = 1.0f / (FACT[p] * FACT[p]);       // compile-time
            Y0[p] = fmaf(-dd[p], dd[p], omul(aa[p], aa[p])) * cpq;
        }
        float hl = x0c;                                 // == h[0]
#pragma unroll
        for (int l = 0; l <= NL; ++l) {
            float sr = 0.f;
#pragma unroll
            for (int p = 0; p <= 4; ++p) {
                if (2 * p <= l) {
                    const float is = 1.0f / FACT[l - 2 * p];    // 9 uniques
                    sr = fmaf(Y0[p], is, sr);
                }
            }
            acc0[l] = fmaf(sr, hl, acc0[l]);
            if (l < NL) {                               // skip dead tail mul
                hl = hl * inv;                          // == h[l+1], exact chain
                asm("" : "+v"(hl));
            }
        }
    }

    // ---- m >= 1: packed (real, imag) ----
    float hbase = x0c;                                  // will become h[m]
#pragma unroll
    for (int m = 1; m <= NL; ++m) {
        hbase = hbase * inv;                            // == h[m], exact chain
        asm("" : "+v"(hbase));
        f32x2 Y[9];
#pragma unroll
        for (int p = 0; p <= NL; ++p) {
            if (p >= m && 2 * p - m <= NL) {
                const int q = p - m;
                const float cpq = 1.0f / (FACT[p] * FACT[q]);   // compile-time
                const float bc = bb[p] * cc[q];
                const f32x2 A = { -dd[q], aa[p] };
                const f32x2 B = {  dd[q], dd[q] };
                const f32x2 C = { omul(aa[p], aa[p]), bc };
                Y[p] = pkfma(A, B, C) * sp(cpq);
            }
        }
        float hl = hbase;                               // == h[m]
#pragma unroll
        for (int l = m; l <= NL; ++l) {
            f32x2 s = sp(0.f);
#pragma unroll
            for (int p = 0; p <= NL; ++p) {
                if (p >= m && 2 * p - m <= l) {
                    const float is = 1.0f / FACT[l - 2 * p + m]; // 9 uniques
                    s = pkfma(Y[p], sp(is), s);
                }
            }
            // accp index: t(l,m) = l*(l-1)/2 + (m-1)
            const int ai = l * (l - 1) / 2 + (m - 1);
            accp[ai] = pkfma(s, sp(hl), accp[ai]);
            if (l < NL) {                               // skip dead tail mul
                hl = hl * inv;                          // == h[l+1], exact chain
                asm("" : "+v"(hl));
            }
        }
    }
}

__global__ __launch_bounds__(256, 1)
void sht_main(const float* __restrict__ pos, int n) {
    float acc0[9];
    f32x2 accp[36];
#pragma unroll
    for (int i = 0; i < 9; ++i) acc0[i] = 0.f;
#pragma unroll
    for (int i = 0; i < 36; ++i) accp[i] = sp(0.f);

    const int t = blockIdx.x * NTHR + threadIdx.x;
    const int nthreads = NBLK * NTHR;                       // 262144
    const int nchunks = (n / 8 + nthreads - 1) / nthreads;  // 2 for N=2^22

    // Same ownership & order as R9/R13/R15 (thread owns 8 contiguous points
    // per chunk, in order) -> bit-identical accumulation. unroll 2: two
    // independent point bodies per iteration for the scheduler to interleave
    // (cross-point ILP) while staying I$-resident (~6-10KB body).
    for (int c = 0; c < nchunks; ++c) {
        const int idx = (c * nthreads + t) * 8;             // 8 contiguous points
#pragma unroll 2
        for (int k = 0; k < 8; ++k) {
            const int i = idx + k;
            float x, y, z;
            if (i < n) {
                x = pos[3 * i + 0];                         // dwordx3; k and k+1
                y = pos[3 * i + 1];                         // share cache lines
                z = pos[3 * i + 2];
            } else {
                x = 0.f; y = 0.f; z = 0.f;                  // zero-pad: adds 0
            }
            point_body(x, y, z, acc0, accp);
        }
    }

    // ---- reduction: wave shuffle -> LDS across 4 waves -> per-block row ----
    __shared__ float red[81][5];   // [out slot][wave], padded stride
    const int lane = threadIdx.x & 63;
    const int wave = threadIdx.x >> 6;

#pragma unroll
    for (int l = 0; l <= NL; ++l) {
        float vr = waveReduce(acc0[l]);
        if (lane == 0) red[l * l + l][wave] = vr;
    }
#pragma unroll
    for (int m = 1; m <= NL; ++m) {
#pragma unroll
        for (int l = m; l <= NL; ++l) {
            const int ai = l * (l - 1) / 2 + (m - 1);
            float vr = waveReduce(accp[ai].x);
            if (lane == 0) red[l * l + l + m][wave] = vr;
            float vi = waveReduce(accp[ai].y);
            if (lane == 0) red[l * l + l - m][wave] = vi;
        }
    }
    __syncthreads();

    // transposed partials: g_ws[slot*NBLK + block]; every slot fully written
    // each launch before finalize reads -> no cross-iteration state.
    if ((int)threadIdx.x < 81) {
        float s = 0.f;
#pragma unroll
        for (int w = 0; w < 4; ++w) s += red[threadIdx.x][w];
        g_ws[threadIdx.x * NBLK + blockIdx.x] = s;
    }
}

__device__ double dfact(int nn) {
    double r = 1.0;
    for (int i = 2; i <= nn; ++i) r *= (double)i;
    return r;
}

// one block per output slot; 256 threads sum 1024 coalesced partials
__global__ __launch_bounds__(256)
void sht_finalize(float* __restrict__ out) {
    const int j = blockIdx.x;       // 0..80
    const int t = threadIdx.x;
    float s = 0.f;
#pragma unroll
    for (int k = 0; k < NBLK / 256; ++k)
        s += g_ws[j * NBLK + k * 256 + t];
    s = waveReduce(s);

    __shared__ float red[4];
    const int lane = t & 63, wave = t >> 6;
    if (lane == 0) red[wave] = s;
    __syncthreads();
    if (t == 0) {
        float tot = red[0] + red[1] + red[2] + red[3];
        int l = 0;
        while ((l + 1) * (l + 1) <= j) ++l;
        const int M = j - l * l - l;
        const int m = (M < 0) ? -M : M;
        // f = sqrt((l+m)!(l-m)!); k_l = sqrt((2l+1)/(4*3.14159))  (ref PI=3.14159)
        double sc = sqrt(dfact(l + m) * dfact(l - m)) *
                    sqrt((double)(2 * l + 1) / (4.0 * 3.14159));
        if (m > 0) sc *= sqrt(2.0) * ((m & 1) ? -1.0 : 1.0);
        out[j] = (float)((double)tot * sc);
    }
}

extern "C" void kernel_launch(void* const* d_in, const int* in_sizes, int n_in,
                              void* d_out, int out_size, void* d_ws, size_t ws_size,
                              hipStream_t stream) {
    const float* pos = (const float*)d_in[0];
    const int npts = in_sizes[0] / 3;
    float* out = (float*)d_out;
    (void)d_ws; (void)ws_size;     // unused (g_ws); the 268MB workspace fill
                                   // is unconditional either way (R18)

    sht_main<<<NBLK, NTHR, 0, stream>>>(pos, npts);
    sht_finalize<<<81, 256, 0, stream>>>(out);
}

// Round 11
// 133.474 us; speedup vs baseline: 1.1417x; 1.1417x over previous
//
#include <hip/hip_runtime.h>
#include <math.h>

// Problem: SphericalHarmonicTransform, L=8, RCUT=5, N=4194304 points.
// R20: R18 + one-point software pipeline on the LOADS (preload k+1 before
//     computing k). R19's unroll-2 spilled (WRITE 150MB, busy 30%) ->
//     reverted; unroll ladder closed {1:70.5 best, 2:spill, 8:I$-thrash}.
//     Roofline recount: ~221 pk + ~105 scalar VALU/point => even at 4cyc/pk
//     the VALU pipe is only ~41% occupied at 70us -> NOT FLOP-bound; real
//     latency stalls remain. The never-isolated source in the unroll-1
//     regime: per-point load wait. #pragma unroll 1's back-edge stops the
//     compiler hoisting k+1's 3 global_loads above k's ~1000cyc body, so
//     every point opens with an L1/L2 wait, poorly covered by 2 waves.
//     (R4's "prefetch bad" was the 8-unrolled I$-thrash regime - N/A.)
//     This round: rotate loads one point ahead (3 regs), values and fold
//     order bit-identical.
//     Predicted: VGPR 72->~78, WRITE ~2.6MB (guard); if VMEM-wait real:
//     busy 49->55-62%, main 70->61-65us, bench ~125. If neutral: pure
//     ALU-dep latency confirmed -> LDS staging or declare floor. absmax 0.0.
// Harness facts: 41us unconditional 268MB d_ws poison-fill in timed window;
//     dur = 41 + main + 4(fin) + ~17(gaps).
// Known-good: unroll-1 point loop (R13); g_ws device scratch (R18, neutral).
// Known-bad: occupancy knobs (R9/R11/R15/R16 busy pinned ~49%); unroll 2
//     (R19 spill); (256,4) fat-kernel spill (R2); waves_per_eu (R10); f32x4
//     packing (R12); pair-packed split (R17); (l,m) split (R16); reshape
//     (R8); fused finalize (R5); old-regime prefetch (R4).

typedef float f32x2 __attribute__((ext_vector_type(2)));

#define NL 8               // L
#define NBLK 1024
#define NTHR 256

// module-scope scratch: replaces d_ws (neutral vs d_ws, kept).
__device__ float g_ws[81 * NBLK];

__device__ __forceinline__ f32x2 sp(float v) { return f32x2{v, v}; }

__device__ __forceinline__ f32x2 pkfma(f32x2 a, f32x2 b, f32x2 c) {
    return __builtin_elementwise_fma(a, b, c);
}

// a*b with an opaque SSA def: blocks GVN/CSE from rebuilding a table of
// these products across the unrolled m-loop. Zero extra instructions,
// bitwise-identical value.
__device__ __forceinline__ float omul(float a, float b) {
    float r = a * b;
    asm("" : "+v"(r));
    return r;
}

__device__ __forceinline__ float waveReduce(float v) {
    v += __shfl_down(v, 32);
    v += __shfl_down(v, 16);
    v += __shfl_down(v, 8);
    v += __shfl_down(v, 4);
    v += __shfl_down(v, 2);
    v += __shfl_down(v, 1);
    return v;
}

// One point, fully unrolled. acc0 = m=0 reals (9); accp = m>=1 (re,im) pairs (36).
// Arithmetic bit-identical to R9/R13/R15/R18.
__device__ __forceinline__ void point_body(float x, float y, float z,
                                           float* __restrict__ acc0,
                                           f32x2* __restrict__ accp) {
    const float FACT[9] = {1.f, 1.f, 2.f, 6.f, 24.f, 120.f, 720.f, 5040.f, 40320.f};

    const float r2 = x * x + y * y + z * z;
    const bool valid = r2 > 0.0f;
    const float inv0 = __builtin_amdgcn_rsqf(r2);      // 1/sqrt(r2)
    const float norm = r2 * inv0;                      // sqrt(r2); NaN at 0, masked
    float cut = 0.5f * (__cosf(norm * 0.6283185307179586f) + 1.0f);
    cut = (r2 > 25.0f) ? 0.0f : cut;
    cut = valid ? cut : 0.0f;                          // kills NaN at r2=0
    const float inv = valid ? inv0 : 1.0f;             // safe 1/norm
    const float x0c = z * cut;

    // packed chains: lane0 = z1 (xp), lane1 = z2 (xm)
    const f32x2 w  = { -0.5f * x,  0.5f * x };         // (xpr, xmr)
    const f32x2 wi = { -0.5f * y, -0.5f * y };         // (xpi, xmi)

    // powcmplx replication:
    //  n=0 -> (1,0); n=1 -> w; n=2 -> special (r^2-i^2, 2ri);
    //  n>=3 -> buggy chain: nr = wr*br - wi*bi; ni = wr*bi + wi*nr (uses NEW nr)
    f32x2 zr[9], zi[9];
    zr[0] = sp(1.f); zi[0] = sp(0.f);
    zr[1] = w;       zi[1] = wi;
    zr[2] = w * w - wi * wi;
    zi[2] = (w + w) * wi;                              // 2*wr*wi
    {
        f32x2 cr = zr[2];
        f32x2 ci = w * wi + wi * cr;                   // buggy chain imag at k=2
#pragma unroll
        for (int k = 3; k <= NL; ++k) {
            const f32x2 nr = w * cr - wi * ci;
            const f32x2 ni = w * ci + wi * nr;         // buggy: uses nr
            cr = nr; ci = ni;
            zr[k] = nr; zi[k] = ni;
        }
    }

    // unpack views (register aliases, free). No sqa table (R15): aa*aa
    // recomputed at each use via omul (bitwise-identical product).
    float aa[9], bb[9], cc[9], dd[9];
#pragma unroll
    for (int p = 0; p <= NL; ++p) {
        aa[p] = zr[p].x;   // z1r
        cc[p] = zr[p].y;   // z2r
        bb[p] = zi[p].x;   // z1i
        dd[p] = zi[p].y;   // z2i
    }

    // No h table (R15): running products reproduce h[l] = h[l-1]*inv exactly.

    // ---- m = 0: pure-real scalar path (no dead imag work) ----
    {
        float Y0[5];                                    // p = q, p <= 4
#pragma unroll
        for (int p = 0; p <= 4; ++p) {
            const float cpq = 1.0f / (FACT[p] * FACT[p]);       // compile-time
            Y0[p] = fmaf(-dd[p], dd[p], omul(aa[p], aa[p])) * cpq;
        }
        float hl = x0c;                                 // == h[0]
#pragma unroll
        for (int l = 0; l <= NL; ++l) {
            float sr = 0.f;
#pragma unroll
            for (int p = 0; p <= 4; ++p) {
                if (2 * p <= l) {
                    const float is = 1.0f / FACT[l - 2 * p];    // 9 uniques
                    sr = fmaf(Y0[p], is, sr);
                }
            }
            acc0[l] = fmaf(sr, hl, acc0[l]);
            if (l < NL) {                               // skip dead tail mul
                hl = hl * inv;                          // == h[l+1], exact chain
                asm("" : "+v"(hl));
            }
        }
    }

    // ---- m >= 1: packed (real, imag) ----
    float hbase = x0c;                                  // will become h[m]
#pragma unroll
    for (int m = 1; m <= NL; ++m) {
        hbase = hbase * inv;                            // == h[m], exact chain
        asm("" : "+v"(hbase));
        f32x2 Y[9];
#pragma unroll
        for (int p = 0; p <= NL; ++p) {
            if (p >= m && 2 * p - m <= NL) {
                const int q = p - m;
                const float cpq = 1.0f / (FACT[p] * FACT[q]);   // compile-time
                const float bc = bb[p] * cc[q];
                const f32x2 A = { -dd[q], aa[p] };
                const f32x2 B = {  dd[q], dd[q] };
                const f32x2 C = { omul(aa[p], aa[p]), bc };
                Y[p] = pkfma(A, B, C) * sp(cpq);
            }
        }
        float hl = hbase;                               // == h[m]
#pragma unroll
        for (int l = m; l <= NL; ++l) {
            f32x2 s = sp(0.f);
#pragma unroll
            for (int p = 0; p <= NL; ++p) {
                if (p >= m && 2 * p - m <= l) {
                    const float is = 1.0f / FACT[l - 2 * p + m]; // 9 uniques
                    s = pkfma(Y[p], sp(is), s);
                }
            }
            // accp index: t(l,m) = l*(l-1)/2 + (m-1)
            const int ai = l * (l - 1) / 2 + (m - 1);
            accp[ai] = pkfma(s, sp(hl), accp[ai]);
            if (l < NL) {                               // skip dead tail mul
                hl = hl * inv;                          // == h[l+1], exact chain
                asm("" : "+v"(hl));
            }
        }
    }
}

__global__ __launch_bounds__(256, 1)
void sht_main(const float* __restrict__ pos, int n) {
    float acc0[9];
    f32x2 accp[36];
#pragma unroll
    for (int i = 0; i < 9; ++i) acc0[i] = 0.f;
#pragma unroll
    for (int i = 0; i < 36; ++i) accp[i] = sp(0.f);

    const int t = blockIdx.x * NTHR + threadIdx.x;
    const int nthreads = NBLK * NTHR;                       // 262144
    const int nchunks = (n / 8 + nthreads - 1) / nthreads;  // 2 for N=2^22

    // Same ownership & order as R9..R18 (thread owns 8 contiguous points per
    // chunk, in order) -> bit-identical accumulation. Load rotation: point
    // k+1's x,y,z are loaded BEFORE point k's body so the ~1000cyc body
    // hides the load latency (the unroll-1 back-edge otherwise forces each
    // point to open with a load wait).
    for (int c = 0; c < nchunks; ++c) {
        const int idx = (c * nthreads + t) * 8;             // 8 contiguous points
        float nx, ny, nz;                                   // preloaded k=0
        if (idx < n) {
            nx = pos[3 * idx + 0];
            ny = pos[3 * idx + 1];
            nz = pos[3 * idx + 2];
        } else {
            nx = 0.f; ny = 0.f; nz = 0.f;                   // zero-pad: adds 0
        }
#pragma unroll 1
        for (int k = 0; k < 8; ++k) {
            const float x = nx, y = ny, z = nz;             // current point
            const int i2 = idx + k + 1;                     // next point
            if (k < 7 && i2 < n) {                          // issue next loads
                nx = pos[3 * i2 + 0];                       // early; waitcnt
                ny = pos[3 * i2 + 1];                       // lands next iter
                nz = pos[3 * i2 + 2];
            } else {
                nx = 0.f; ny = 0.f; nz = 0.f;
            }
            point_body(x, y, z, acc0, accp);
        }
    }

    // ---- reduction: wave shuffle -> LDS across 4 waves -> per-block row ----
    __shared__ float red[81][5];   // [out slot][wave], padded stride
    const int lane = threadIdx.x & 63;
    const int wave = threadIdx.x >> 6;

#pragma unroll
    for (int l = 0; l <= NL; ++l) {
        float vr = waveReduce(acc0[l]);
        if (lane == 0) red[l * l + l][wave] = vr;
    }
#pragma unroll
    for (int m = 1; m <= NL; ++m) {
#pragma unroll
        for (int l = m; l <= NL; ++l) {
            const int ai = l * (l - 1) / 2 + (m - 1);
            float vr = waveReduce(accp[ai].x);
            if (lane == 0) red[l * l + l + m][wave] = vr;
            float vi = waveReduce(accp[ai].y);
            if (lane == 0) red[l * l + l - m][wave] = vi;
        }
    }
    __syncthreads();

    // transposed partials: g_ws[slot*NBLK + block]; every slot fully written
    // each launch before finalize reads -> no cross-iteration state.
    if ((int)threadIdx.x < 81) {
        float s = 0.f;
#pragma unroll
        for (int w = 0; w < 4; ++w) s += red[threadIdx.x][w];
        g_ws[threadIdx.x * NBLK + blockIdx.x] = s;
    }
}

__device__ double dfact(int nn) {
    double r = 1.0;
    for (int i = 2; i <= nn; ++i) r *= (double)i;
    return r;
}

// one block per output slot; 256 threads sum 1024 coalesced partials
__global__ __launch_bounds__(256)
void sht_finalize(float* __restrict__ out) {
    const int j = blockIdx.x;       // 0..80
    const int t = threadIdx.x;
    float s = 0.f;
#pragma unroll
    for (int k = 0; k < NBLK / 256; ++k)
        s += g_ws[j * NBLK + k * 256 + t];
    s = waveReduce(s);

    __shared__ float red[4];
    const int lane = t & 63, wave = t >> 6;
    if (lane == 0) red[wave] = s;
    __syncthreads();
    if (t == 0) {
        float tot = red[0] + red[1] + red[2] + red[3];
        int l = 0;
        while ((l + 1) * (l + 1) <= j) ++l;
        const int M = j - l * l - l;
        const int m = (M < 0) ? -M : M;
        // f = sqrt((l+m)!(l-m)!); k_l = sqrt((2l+1)/(4*3.14159))  (ref PI=3.14159)
        double sc = sqrt(dfact(l + m) * dfact(l - m)) *
                    sqrt((double)(2 * l + 1) / (4.0 * 3.14159));
        if (m > 0) sc *= sqrt(2.0) * ((m & 1) ? -1.0 : 1.0);
        out[j] = (float)((double)tot * sc);
    }
}

extern "C" void kernel_launch(void* const* d_in, const int* in_sizes, int n_in,
                              void* d_out, int out_size, void* d_ws, size_t ws_size,
                              hipStream_t stream) {
    const float* pos = (const float*)d_in[0];
    const int npts = in_sizes[0] / 3;
    float* out = (float*)d_out;
    (void)d_ws; (void)ws_size;     // unused (g_ws); the 268MB workspace fill
                                   // is unconditional either way (R18)

    sht_main<<<NBLK, NTHR, 0, stream>>>(pos, npts);
    sht_finalize<<<81, 256, 0, stream>>>(out);
}